// Round 4
// baseline (673.803 us; speedup 1.0000x reference)
//
#include <hip/hip_runtime.h>

// RobustSum: M = A@V; 3x { dist=cdist(M,V); w=1/(dist+eps); ww=w*A;
//                          M = (ww/rowsum(ww)) @ V }   (T=1.0)
// bf16 MFMA; tolerance = 2% of ref absmax.
//
// Round 12: r11 with the VGPR budget fixed. r11's __launch_bounds__(512,4)
// imposed a 128-VGPR cap while mreg[2][16] alone is 128 VGPRs -> guaranteed
// scratch spill of the M-operand -> pathological slowdown (container
// timeout). A 512-thread block needs 2 waves/SIMD, which is the <=256-VGPR
// occupancy step -> __launch_bounds__(512, 2) is the correct cap.
// Everything else identical to r11:
//   fused per-iteration kernel: ph1 P=M@V^T (M register-resident, B1 LDS
//   dbuf), dist/weight epilogue in regs, W -> LDS only (never HBM),
//   ph2 Macc += W @ Vt (reg-staged swizzled Bt), split-K=4 j-slices ->
//   bf16 partials + 4-slot l1p -> shared reduce.

typedef __bf16 bf16;
typedef bf16 bf16x4 __attribute__((ext_vector_type(4)));
typedef bf16 bf16x8 __attribute__((ext_vector_type(8)));
typedef float f32x4 __attribute__((ext_vector_type(4)));

#define S_DIM 2048
#define D_DIM 512
#define NB    4
#define EPSILON 0.01f

#define AS1 __attribute__((address_space(1)))
#define AS3 __attribute__((address_space(3)))

// ---------------- cast fp32 -> bf16 (vectorized x4) ----------------
__global__ void cast_kernel(const float* __restrict__ in, bf16* __restrict__ out, int n4) {
  int i = blockIdx.x * blockDim.x + threadIdx.x;
  if (i >= n4) return;
  float4 v = ((const float4*)in)[i];
  bf16x4 o = { (bf16)v.x, (bf16)v.y, (bf16)v.z, (bf16)v.w };
  ((bf16x4*)out)[i] = o;
}

// -- V preproc: V fp32 -> Vbf + Vt (bf16) + v2 row L2^2 (non-atomic) --
__global__ void vprep_kernel(const float* __restrict__ V, bf16* __restrict__ Vbf,
                             bf16* __restrict__ Vt, float* __restrict__ v2) {
  __shared__ float tile[64][68];
  int b  = blockIdx.y;
  int r0 = blockIdx.x * 64;
  const float* Vb = V   + (size_t)b * S_DIM * D_DIM;
  bf16*       Vfb = Vbf + (size_t)b * S_DIM * D_DIM;
  bf16*       Vtb = Vt  + (size_t)b * S_DIM * D_DIM;
  float*      v2b = v2  + (size_t)b * S_DIM;
  int tx = threadIdx.x & 15, ty = threadIdx.x >> 4;   // ty 0..15
  float acc2[4] = { 0.f, 0.f, 0.f, 0.f };
  for (int c = 0; c < 8; ++c) {
    int c0 = c * 64;
#pragma unroll
    for (int i = 0; i < 4; ++i) {
      int r = ty + i * 16;
      float4 v = *(const float4*)(Vb + (size_t)(r0 + r) * D_DIM + (c0 + tx * 4));
      tile[r][tx * 4 + 0] = v.x; tile[r][tx * 4 + 1] = v.y;
      tile[r][tx * 4 + 2] = v.z; tile[r][tx * 4 + 3] = v.w;
      bf16x4 o = { (bf16)v.x, (bf16)v.y, (bf16)v.z, (bf16)v.w };
      *(bf16x4*)(Vfb + (size_t)(r0 + r) * D_DIM + (c0 + tx * 4)) = o;
#pragma unroll
      for (int j = 0; j < 4; ++j) { float f = (float)o[j]; acc2[i] += f * f; }
    }
    __syncthreads();
#pragma unroll
    for (int i = 0; i < 4; ++i) {
      int cc = ty + i * 16;
      bf16x4 o = { (bf16)tile[tx * 4 + 0][cc], (bf16)tile[tx * 4 + 1][cc],
                   (bf16)tile[tx * 4 + 2][cc], (bf16)tile[tx * 4 + 3][cc] };
      *(bf16x4*)(Vtb + (size_t)(c0 + cc) * S_DIM + (r0 + tx * 4)) = o;
    }
    __syncthreads();
  }
#pragma unroll
  for (int i = 0; i < 4; ++i) {
    float s = acc2[i];
    s += __shfl_xor(s, 1); s += __shfl_xor(s, 2);
    s += __shfl_xor(s, 4); s += __shfl_xor(s, 8);
    if (tx == 0) v2b[r0 + ty + i * 16] = s;
  }
}

// ---------------- fused iteration kernel v2 (VGPR-fixed) ----------------
// grid (js 4, ir 32, b 4) = 512 blocks, 512 threads (8 waves), 64 KiB LDS.
// 2 waves/SIMD (<=256 VGPR) -> 1 block/CU, 2 sequential rounds.
__global__ __launch_bounds__(512, 2)
void fused_kernel(const bf16* __restrict__ Mbf, const bf16* __restrict__ Vbf,
                  const bf16* __restrict__ Vt, const bf16* __restrict__ Abf,
                  const float* __restrict__ m2, const float* __restrict__ v2,
                  bf16* __restrict__ part, float* __restrict__ l1p) {
  const int b  = blockIdx.z;
  const int i0 = blockIdx.y * 64;
  const int js = blockIdx.x;           // 0..3 -> j quarter (split-K slice)
  const int jbase = js * 512;

  const bf16* Mb = Mbf + (size_t)b * S_DIM * D_DIM;
  const bf16* Vb = Vbf + (size_t)b * S_DIM * D_DIM;
  const bf16* Tb = Vt  + (size_t)b * S_DIM * D_DIM;   // [d][s]
  const bf16* Ab = Abf + (size_t)b * S_DIM * S_DIM;
  const float* m2b = m2 + (size_t)b * S_DIM;
  const float* v2b = v2 + (size_t)b * S_DIM;

  __shared__ bf16 smem[32768];             // 64 KiB
  bf16* B1 = smem;                         // 2 x [128 j][64 k], 16 KB each
  bf16* Wt = smem;                         // [64 i][128 j] = 16 KB (== buf0; safe:
                                           //  kt7 reads buf1 only, jt-top barrier)
  bf16* Bt = smem + 16384;                 // [128 d][128 j] = 32 KB
  float* l1lds = (float*)(smem + 8192);    // byte 16384 (buf1), 256 f32, final only
  float* slab  = (float*)(smem + 16384);   // byte 32768 (Bt), 16x512 f32, final only

  const int tid  = threadIdx.x;
  const int w    = tid >> 6;      // wave 0..7
  const int lane = tid & 63;
  const int iw   = w >> 2;        // 0..1 -> 32-row half   (ph1 & ph2)
  const int jw   = w & 3;         // 0..3 -> 32-col quarter (ph1 j / ph2 d)
  const int q    = lane >> 4;
  const int c16  = lane & 15;
  const int x7   = c16 & 7;
  const int srow  = lane >> 3;           // staging (8-row)
  const int schk  = (lane & 7) ^ srow;   // pre-swizzled source chunk
  const int srow4 = lane >> 4;           // staging (4-row, 16 chunks)
  const int lchk  = lane & 15;

  // ---- M resident in registers: mreg[mi][t] = M[i0+iw*32+mi*16+c16][t*32+q*8 ..+7]
  bf16x8 mreg[2][16];
#pragma unroll
  for (int mi = 0; mi < 2; ++mi) {
    const bf16* mr = Mb + (size_t)(i0 + iw * 32 + mi * 16 + c16) * D_DIM;
#pragma unroll
    for (int t = 0; t < 16; ++t)
      mreg[mi][t] = *(const bf16x8*)(mr + t * 32 + q * 8);
  }
  float m2v[2][4];
#pragma unroll
  for (int mi = 0; mi < 2; ++mi)
#pragma unroll
    for (int r = 0; r < 4; ++r)
      m2v[mi][r] = m2b[i0 + iw * 32 + mi * 16 + q * 4 + r];

  f32x4 acc2[4][2][2] = {};      // [ch][mi][nd]: i=iw*32+mi*16+q*4+r, d=ch*128+jw*32+nd*16+c16
  float l1acc[2][4] = {};
  uint4 btr[4];

  for (int jt = 0; jt < 4; ++jt) {
    const int j0 = jbase + jt * 128;
    __builtin_amdgcn_s_barrier();        // prev jt ph2 readers done (Wt/Bt)

    // stage B1 kt=0 -> buf0 ; issue Bt ch0 -> regs
#pragma unroll
    for (int it = 0; it < 2; ++it)
      __builtin_amdgcn_global_load_lds(
          (const AS1 void*)(Vb + (size_t)(j0 + it * 64 + w * 8 + srow) * D_DIM + schk * 8),
          (AS3 void*)(B1 + (it * 64 + w * 8) * 64), 16, 0, 0);
#pragma unroll
    for (int it = 0; it < 4; ++it)
      btr[it] = *(const uint4*)(Tb + (size_t)(it * 32 + w * 4 + srow4) * S_DIM + j0 + lchk * 8);

    // ---- phase 1: P(64x128) over K=512, B1 double-buffered, M from regs ----
    f32x4 acc1[2][2] = {};
#pragma unroll
    for (int kt = 0; kt < 8; ++kt) {
      asm volatile("s_waitcnt vmcnt(0)" ::: "memory");   // stage(kt) landed
      __builtin_amdgcn_s_barrier();
      if (kt < 7) {
#pragma unroll
        for (int it = 0; it < 2; ++it)
          __builtin_amdgcn_global_load_lds(
              (const AS1 void*)(Vb + (size_t)(j0 + it * 64 + w * 8 + srow) * D_DIM + (kt + 1) * 64 + schk * 8),
              (AS3 void*)(B1 + ((kt & 1) ^ 1) * 8192 + (it * 64 + w * 8) * 64), 16, 0, 0);
      }
      const bf16* lb = B1 + (kt & 1) * 8192;
      __builtin_amdgcn_s_setprio(1);
#pragma unroll
      for (int kk = 0; kk < 2; ++kk) {
        const int p = ((kk << 2) + q) ^ x7;
        bf16x8 bfr[2];
#pragma unroll
        for (int nj = 0; nj < 2; ++nj)
          bfr[nj] = *(const bf16x8*)(lb + (jw * 32 + nj * 16 + c16) * 64 + p * 8);
#pragma unroll
        for (int mi = 0; mi < 2; ++mi)
#pragma unroll
          for (int nj = 0; nj < 2; ++nj)
            acc1[mi][nj] = __builtin_amdgcn_mfma_f32_16x16x32_bf16(
                mreg[mi][kt * 2 + kk], bfr[nj], acc1[mi][nj], 0, 0, 0);
      }
      __builtin_amdgcn_s_setprio(0);
    }

    // ---- epilogue: w = rcp(sqrt(max(m2+v2-2P,0))+eps); x = w*A; Wt (buf0) ----
    float v2v[2];
#pragma unroll
    for (int nj = 0; nj < 2; ++nj) v2v[nj] = v2b[j0 + jw * 32 + nj * 16 + c16];
#pragma unroll
    for (int mi = 0; mi < 2; ++mi)
#pragma unroll
      for (int nj = 0; nj < 2; ++nj)
#pragma unroll
        for (int r = 0; r < 4; ++r) {
          const int rr = iw * 32 + mi * 16 + q * 4 + r;
          const int jl = jw * 32 + nj * 16 + c16;
          float d2 = fmaxf(m2v[mi][r] + v2v[nj] - 2.f * acc1[mi][nj][r], 0.f);
          float w_ = __builtin_amdgcn_rcpf(__builtin_amdgcn_sqrtf(d2) + EPSILON);
          float a  = (float)Ab[(size_t)(i0 + rr) * S_DIM + j0 + jl];
          float x  = w_ * a;
          l1acc[mi][r] += fabsf(x);
          Wt[rr * 128 + (((jl >> 3) ^ (rr & 7)) << 3) + (jl & 7)] = (bf16)x;
        }
    // Bt ch0 write (btr landed via kt-loop waits) + issue ch1
#pragma unroll
    for (int it = 0; it < 4; ++it) {
      int row = it * 32 + w * 4 + srow4;
      *(uint4*)(Bt + row * 128 + ((lchk ^ (row & 7)) << 3)) = btr[it];
    }
#pragma unroll
    for (int it = 0; it < 4; ++it)
      btr[it] = *(const uint4*)(Tb + (size_t)(128 + it * 32 + w * 4 + srow4) * S_DIM + j0 + lchk * 8);
    asm volatile("s_waitcnt lgkmcnt(0)" ::: "memory");
    __builtin_amdgcn_s_barrier();

    // ---- phase 2: Macc += W(64x128) @ Vt-chunks (4 x 128d), 2x2 tiles ----
#pragma unroll
    for (int ch = 0; ch < 4; ++ch) {
      __builtin_amdgcn_s_setprio(1);
#pragma unroll
      for (int kk = 0; kk < 4; ++kk) {
        const int p = ((kk << 2) + q) ^ x7;
        bf16x8 aw[2], bv[2];
#pragma unroll
        for (int mi = 0; mi < 2; ++mi)
          aw[mi] = *(const bf16x8*)(Wt + (iw * 32 + mi * 16 + c16) * 128 + p * 8);
#pragma unroll
        for (int nd = 0; nd < 2; ++nd)
          bv[nd] = *(const bf16x8*)(Bt + (jw * 32 + nd * 16 + c16) * 128 + p * 8);
#pragma unroll
        for (int mi = 0; mi < 2; ++mi)
#pragma unroll
          for (int nd = 0; nd < 2; ++nd)
            acc2[ch][mi][nd] = __builtin_amdgcn_mfma_f32_16x16x32_bf16(
                aw[mi], bv[nd], acc2[ch][mi][nd], 0, 0, 0);
      }
      __builtin_amdgcn_s_setprio(0);
      if (ch < 3) {
        __builtin_amdgcn_s_barrier();                     // all done reading Bt[ch]
        asm volatile("s_waitcnt vmcnt(0)" ::: "memory");  // btr ch+1 landed
#pragma unroll
        for (int it = 0; it < 4; ++it) {
          int row = it * 32 + w * 4 + srow4;
          *(uint4*)(Bt + row * 128 + ((lchk ^ (row & 7)) << 3)) = btr[it];
        }
        if (ch < 2) {
#pragma unroll
          for (int it = 0; it < 4; ++it)
            btr[it] = *(const uint4*)(Tb + (size_t)((ch + 2) * 128 + it * 32 + w * 4 + srow4) * S_DIM + j0 + lchk * 8);
        }
        asm volatile("s_waitcnt lgkmcnt(0)" ::: "memory");
        __builtin_amdgcn_s_barrier();
      }
    }
  }

  // ---- final: l1 merge -> l1p ; Macc -> bf16 partial via slab ----
  __builtin_amdgcn_s_barrier();     // last jt's Wt/Bt reads done
#pragma unroll
  for (int mi = 0; mi < 2; ++mi)
#pragma unroll
    for (int r = 0; r < 4; ++r) {
      float s = l1acc[mi][r];
      s += __shfl_xor(s, 1); s += __shfl_xor(s, 2);
      s += __shfl_xor(s, 4); s += __shfl_xor(s, 8);
      if (c16 == 0) l1lds[jw * 64 + iw * 32 + mi * 16 + q * 4 + r] = s;
    }
  asm volatile("s_waitcnt lgkmcnt(0)" ::: "memory");
  __builtin_amdgcn_s_barrier();
  if (tid < 64)
    l1p[((size_t)js * NB + b) * S_DIM + i0 + tid] =
        l1lds[tid] + l1lds[64 + tid] + l1lds[128 + tid] + l1lds[192 + tid];

  bf16* pp = part + ((size_t)js * NB + b) * (size_t)S_DIM * D_DIM;
#pragma unroll
  for (int g = 0; g < 4; ++g) {
    __builtin_amdgcn_s_barrier();   // slab region free
    if ((g >> 1) == iw) {
      const int mi = g & 1;
#pragma unroll
      for (int ch = 0; ch < 4; ++ch)
#pragma unroll
        for (int nd = 0; nd < 2; ++nd)
#pragma unroll
          for (int r = 0; r < 4; ++r)
            slab[(q * 4 + r) * 512 + ch * 128 + jw * 32 + nd * 16 + c16] = acc2[ch][mi][nd][r];
    }
    asm volatile("s_waitcnt lgkmcnt(0)" ::: "memory");
    __builtin_amdgcn_s_barrier();
    {
      const int row = tid >> 5, col = (tid & 31) * 16;
      const float* sp = slab + row * 512 + col;
      float4 f0 = *(const float4*)(sp + 0);
      float4 f1 = *(const float4*)(sp + 4);
      float4 f2 = *(const float4*)(sp + 8);
      float4 f3 = *(const float4*)(sp + 12);
      bf16x8 o0 = { (bf16)f0.x, (bf16)f0.y, (bf16)f0.z, (bf16)f0.w,
                    (bf16)f1.x, (bf16)f1.y, (bf16)f1.z, (bf16)f1.w };
      bf16x8 o1 = { (bf16)f2.x, (bf16)f2.y, (bf16)f2.z, (bf16)f2.w,
                    (bf16)f3.x, (bf16)f3.y, (bf16)f3.z, (bf16)f3.w };
      bf16* op = pp + (size_t)(i0 + g * 16 + row) * D_DIM + col;
      *(bf16x8*)(op)     = o0;
      *(bf16x8*)(op + 8) = o1;
    }
  }
}

// ---------------- NT GEMM 128^2: split-K=4 bf16 partials (M0 = A@V) ----------------
__global__ __launch_bounds__(256, 4)
void gemm_kernel(const bf16* __restrict__ Amat, const bf16* __restrict__ Bmat,
                 int M, int N, int K, bf16* __restrict__ Cp) {
  const int bz = blockIdx.z >> 2;
  const int ks = blockIdx.z & 3;
  const int kbeg = ks * (K >> 2), kend = kbeg + (K >> 2);
  const int row0 = blockIdx.y * 128;
  const int col0 = blockIdx.x * 128;
  const bf16* Ab = Amat + (size_t)bz * M * K;
  const bf16* Bb = Bmat + (size_t)bz * N * K;

  __shared__ char smem[33792];
  bf16*  ldsA = (bf16*)smem;
  bf16*  ldsB = (bf16*)(smem + 16384);
  float* ldsW = (float*)smem;

  const int tid  = threadIdx.x;
  const int wave = tid >> 6;
  const int lane = tid & 63;
  const int wr   = wave >> 1;
  const int wc   = wave & 1;
  const int q    = lane >> 4;
  const int c16  = lane & 15;
  const int srow = lane >> 3;
  const int scol = ((lane & 7) ^ srow) * 8;

  f32x4 acc[4][4] = {};

  for (int k0 = kbeg; k0 < kend; k0 += 64) {
#pragma unroll
    for (int i = 0; i < 4; ++i) {
      int slot = wave * 4 + i;
      int r = slot * 8 + srow;
      __builtin_amdgcn_global_load_lds(
          (const AS1 void*)(Ab + (size_t)(row0 + r) * K + (k0 + scol)),
          (AS3 void*)(ldsA + slot * 512), 16, 0, 0);
      __builtin_amdgcn_global_load_lds(
          (const AS1 void*)(Bb + (size_t)(col0 + r) * K + (k0 + scol)),
          (AS3 void*)(ldsB + slot * 512), 16, 0, 0);
    }
    __syncthreads();

#pragma unroll
    for (int kk = 0; kk < 2; ++kk) {
      bf16x8 afr[4], bfr[4];
#pragma unroll
      for (int mt = 0; mt < 4; ++mt) {
        int R = wr * 64 + mt * 16 + c16;
        int p = ((kk << 2) + q) ^ (c16 & 7);
        afr[mt] = *(const bf16x8*)(ldsA + (size_t)R * 64 + p * 8);
      }
#pragma unroll
      for (int nt = 0; nt < 4; ++nt) {
        int R = wc * 64 + nt * 16 + c16;
        int p = ((kk << 2) + q) ^ (c16 & 7);
        bfr[nt] = *(const bf16x8*)(ldsB + (size_t)R * 64 + p * 8);
      }
#pragma unroll
      for (int mt = 0; mt < 4; ++mt)
#pragma unroll
        for (int nt = 0; nt < 4; ++nt)
          acc[mt][nt] = __builtin_amdgcn_mfma_f32_16x16x32_bf16(afr[mt], bfr[nt], acc[mt][nt], 0, 0, 0);
    }
    __syncthreads();
  }

  const int lr  = tid >> 3;
  const int sub = tid & 7;
#pragma unroll
  for (int h = 0; h < 2; ++h) {
    __syncthreads();
    if (wr == h) {
#pragma unroll
      for (int mt = 0; mt < 4; ++mt)
#pragma unroll
        for (int nt = 0; nt < 4; ++nt)
#pragma unroll
          for (int r = 0; r < 4; ++r)
            ldsW[(mt * 16 + q * 4 + r) * 132 + wc * 64 + nt * 16 + c16] = acc[mt][nt][r];
    }
    __syncthreads();
#pragma unroll
    for (int h2 = 0; h2 < 2; ++h2) {
      int rloc = lr + 32 * h2;
      int gi = row0 + 64 * h + rloc;
      const float* wp = ldsW + rloc * 132 + sub * 16;
      float4 w0 = *(const float4*)(wp + 0);
      float4 w1 = *(const float4*)(wp + 4);
      float4 w2 = *(const float4*)(wp + 8);
      float4 w3 = *(const float4*)(wp + 12);
      float wv_[16] = { w0.x, w0.y, w0.z, w0.w, w1.x, w1.y, w1.z, w1.w,
                        w2.x, w2.y, w2.z, w2.w, w3.x, w3.y, w3.z, w3.w };
      bf16* Cb = Cp + ((size_t)ks * NB + bz) * ((size_t)M * N);
      bf16x8 o0, o1;
#pragma unroll
      for (int e = 0; e < 8; ++e) { o0[e] = (bf16)wv_[e]; o1[e] = (bf16)wv_[e + 8]; }
      bf16* op = Cb + (size_t)gi * N + (col0 + sub * 16);
      *(bf16x8*)(op)     = o0;
      *(bf16x8*)(op + 8) = o1;
    }
  }
}

// ---------------- reduce split-K=4 bf16 partials ----------------
// RMODE 0: Mbf + m2 ;  1: scale 1/l1 -> Mbf + m2 ;  2: scale 1/l1 -> fp32 out
template <int RMODE>
__global__ void reduce_kernel(const bf16* __restrict__ part, const float* __restrict__ l1p,
                              bf16* __restrict__ Mo, float* __restrict__ Fo,
                              float* __restrict__ m2) {
  int wave = threadIdx.x >> 6, lane = threadIdx.x & 63;
  int rg = blockIdx.x * 4 + wave;          // 0..NB*S-1
  float v[8] = {};
#pragma unroll
  for (int s4 = 0; s4 < 4; ++s4) {
    const bf16* p = part + (size_t)s4 * NB * S_DIM * D_DIM + (size_t)rg * D_DIM + lane * 8;
    bf16x8 a = *(const bf16x8*)p;
#pragma unroll
    for (int e = 0; e < 8; ++e) v[e] += (float)a[e];
  }
  float sc = 1.f;
  if (RMODE >= 1) {
    int bb = rg >> 11, row = rg & (S_DIM - 1);
    float l1v = 0.f;
#pragma unroll
    for (int e = 0; e < 4; ++e) l1v += l1p[((size_t)e * NB + bb) * S_DIM + row];
    sc = __builtin_amdgcn_rcpf(fmaxf(l1v, 1e-12f));
  }
  float s = 0.f;
#pragma unroll
  for (int e = 0; e < 8; ++e) { v[e] *= sc; s += v[e] * v[e]; }
  if (RMODE == 2) {
    float4 o0 = { v[0], v[1], v[2], v[3] }, o1 = { v[4], v[5], v[6], v[7] };
    float* op = Fo + (size_t)rg * D_DIM + lane * 8;
    *(float4*)(op) = o0; *(float4*)(op + 4) = o1;
  } else {
    bf16x8 o;
#pragma unroll
    for (int e = 0; e < 8; ++e) o[e] = (bf16)v[e];
    *(bf16x8*)(Mo + (size_t)rg * D_DIM + lane * 8) = o;
#pragma unroll
    for (int off = 32; off > 0; off >>= 1) s += __shfl_xor(s, off);
    if (lane == 0) m2[rg] = s;
  }
}

extern "C" void kernel_launch(void* const* d_in, const int* in_sizes, int n_in,
                              void* d_out, int out_size, void* d_ws, size_t ws_size,
                              hipStream_t stream) {
  const float* A = (const float*)d_in[0];  // (4, 2048, 2048)
  const float* V = (const float*)d_in[1];  // (4, 2048, 512)
  float* out = (float*)d_out;              // (4, 2048, 512) fp32

  char* ws = (char*)d_ws;
  bf16* Abf = (bf16*)ws;   ws += (size_t)NB * S_DIM * S_DIM * 2;       // 33.5 MB
  bf16* Vbf = (bf16*)ws;   ws += (size_t)NB * S_DIM * D_DIM * 2;       //  8.4 MB
  bf16* Vt  = (bf16*)ws;   ws += (size_t)NB * S_DIM * D_DIM * 2;       //  8.4 MB
  bf16* Mbf = (bf16*)ws;   ws += (size_t)NB * S_DIM * D_DIM * 2;       //  8.4 MB
  bf16* part = (bf16*)ws;  ws += (size_t)4 * NB * S_DIM * D_DIM * 2;   // 33.5 MB
  float* v2 = (float*)ws;  ws += (size_t)NB * S_DIM * 4;
  float* m2 = (float*)ws;  ws += (size_t)NB * S_DIM * 4;
  float* l1p = (float*)ws; ws += (size_t)4 * NB * S_DIM * 4;           // 128 KB

  int nA4 = NB * S_DIM * S_DIM / 4;
  cast_kernel<<<nA4 / 256, 256, 0, stream>>>(A, Abf, nA4);
  vprep_kernel<<<dim3(S_DIM / 64, NB), 256, 0, stream>>>(V, Vbf, Vt, v2);

  // M0 = A @ V  (split-K=4 bf16 partials -> reduce with m2)
  gemm_kernel<<<dim3(D_DIM / 128, S_DIM / 128, NB * 4), 256, 0, stream>>>(
      Abf, Vt, S_DIM, D_DIM, S_DIM, part);
  reduce_kernel<0><<<NB * S_DIM / 4, 256, 0, stream>>>(part, nullptr, Mbf, nullptr, m2);

  for (int it = 0; it < 3; ++it) {
    // fused: P=M@V^T -> w -> W(LDS only) -> M_part = W@V ; l1 partials
    fused_kernel<<<dim3(4, S_DIM / 64, NB), 512, 0, stream>>>(
        Mbf, Vbf, Vt, Abf, m2, v2, part, l1p);
    if (it < 2)
      reduce_kernel<1><<<NB * S_DIM / 4, 256, 0, stream>>>(part, l1p, Mbf, nullptr, m2);
    else
      reduce_kernel<2><<<NB * S_DIM / 4, 256, 0, stream>>>(part, l1p, nullptr, out, nullptr);
  }
}

// Round 5
// 319.392 us; speedup vs baseline: 2.1096x; 2.1096x over previous
//
#include <hip/hip_runtime.h>

// RobustSum: M = A@V; 3x { dist=cdist(M,V); w=1/(dist+eps); ww=w*A;
//                          M = (ww/rowsum(ww)) @ V }   (T=1.0)
// bf16 MFMA; tolerance = 2% of ref absmax (margin: 5.3x).
//
// Round 13: REVERT to the round-0 structure (334us verified; the fused
// variants r10/r12 both lost: W-transpose through LDS + barrier chain +
// occupancy collapse cost more than the 134MB/iter HBM round-trip saved).
// Single change vs round-0: T1 XCD-chunked blockIdx swizzle on both GEMM
// kernels (bijective, nwg%8==0): each XCD gets a contiguous tile chunk ->
// shared row-panels (M-panel in MODE-1, W-panel in MODE-4) become
// L2-resident instead of re-fetched by all 8 XCDs.

typedef __bf16 bf16;
typedef bf16 bf16x4 __attribute__((ext_vector_type(4)));
typedef bf16 bf16x8 __attribute__((ext_vector_type(8)));
typedef float f32x4 __attribute__((ext_vector_type(4)));

#define S_DIM 2048
#define D_DIM 512
#define NB    4
#define EPSILON 0.01f

// ---------------- cast fp32 -> bf16 (vectorized x4) ----------------
__global__ void cast_kernel(const float* __restrict__ in, bf16* __restrict__ out, int n4) {
  int i = blockIdx.x * blockDim.x + threadIdx.x;
  if (i >= n4) return;
  float4 v = ((const float4*)in)[i];
  bf16x4 o = { (bf16)v.x, (bf16)v.y, (bf16)v.z, (bf16)v.w };
  ((bf16x4*)out)[i] = o;
}

// -- V preproc: V fp32 -> Vbf + Vt (bf16) + v2 row L2^2 (non-atomic) --
// One block per 64-row stripe; loops over 8 column chunks of 64.
__global__ void vprep_kernel(const float* __restrict__ V, bf16* __restrict__ Vbf,
                             bf16* __restrict__ Vt, float* __restrict__ v2) {
  __shared__ float tile[64][68];
  int b  = blockIdx.y;
  int r0 = blockIdx.x * 64;
  const float* Vb = V   + (size_t)b * S_DIM * D_DIM;
  bf16*       Vfb = Vbf + (size_t)b * S_DIM * D_DIM;
  bf16*       Vtb = Vt  + (size_t)b * S_DIM * D_DIM;
  float*      v2b = v2  + (size_t)b * S_DIM;
  int tx = threadIdx.x & 15, ty = threadIdx.x >> 4;   // ty 0..15
  float acc2[4] = { 0.f, 0.f, 0.f, 0.f };
  for (int c = 0; c < 8; ++c) {
    int c0 = c * 64;
#pragma unroll
    for (int i = 0; i < 4; ++i) {
      int r = ty + i * 16;
      float4 v = *(const float4*)(Vb + (size_t)(r0 + r) * D_DIM + (c0 + tx * 4));
      tile[r][tx * 4 + 0] = v.x; tile[r][tx * 4 + 1] = v.y;
      tile[r][tx * 4 + 2] = v.z; tile[r][tx * 4 + 3] = v.w;
      bf16x4 o = { (bf16)v.x, (bf16)v.y, (bf16)v.z, (bf16)v.w };
      *(bf16x4*)(Vfb + (size_t)(r0 + r) * D_DIM + (c0 + tx * 4)) = o;
#pragma unroll
      for (int j = 0; j < 4; ++j) { float f = (float)o[j]; acc2[i] += f * f; }
    }
    __syncthreads();
#pragma unroll
    for (int i = 0; i < 4; ++i) {
      int cc = ty + i * 16;
      bf16x4 o = { (bf16)tile[tx * 4 + 0][cc], (bf16)tile[tx * 4 + 1][cc],
                   (bf16)tile[tx * 4 + 2][cc], (bf16)tile[tx * 4 + 3][cc] };
      *(bf16x4*)(Vtb + (size_t)(c0 + cc) * S_DIM + (r0 + tx * 4)) = o;
    }
    __syncthreads();   // tile reused next chunk
  }
  // threads sharing row r are 16 contiguous lanes (tid = ty*16+tx)
#pragma unroll
  for (int i = 0; i < 4; ++i) {
    float s = acc2[i];
    s += __shfl_xor(s, 1); s += __shfl_xor(s, 2);
    s += __shfl_xor(s, 4); s += __shfl_xor(s, 8);
    if (tx == 0) v2b[r0 + ty + i * 16] = s;
  }
}

// ---------------- NT GEMM: C[M,N] = Amat(MxK) * Bmat(NxK)^T, BK=64 ----------------
// MODE 1: P-GEMM (grid z=NB): dist/weight epilogue -> Wbf + l1p slots (16/row).
// MODE 4: split-K=2 (grid z=2*NB): bf16 partial C, vectorized via LDS halves.
// LDS swizzle: 16B chunk p within a 128B row holds logical chunk p ^ (row&7).
// T1: XCD-chunked bijective blockIdx remap within each z-slice (nwg%8==0).
template <int MODE>
__global__ __launch_bounds__(256, 4)
void gemm_kernel(const bf16* __restrict__ Amat, const bf16* __restrict__ Bmat,
                 int M, int N, int K,
                 bf16* __restrict__ Cp,
                 const float* __restrict__ m2, const float* __restrict__ v2,
                 const bf16* __restrict__ Aw, bf16* __restrict__ Wout,
                 float* __restrict__ l1p) {
  int bz, ks, kbeg, kend;
  if (MODE == 4) { bz = blockIdx.z >> 1; ks = blockIdx.z & 1; kbeg = ks * (K >> 1); kend = kbeg + (K >> 1); }
  else           { bz = blockIdx.z;      ks = 0;              kbeg = 0;             kend = K; }

  // T1 XCD-chunked swizzle: XCD k (== lin%8 under round-robin dispatch)
  // processes a CONTIGUOUS chunk of tile ids -> row-panels L2-resident.
  const int gx  = gridDim.x;
  const int nwg = gx * gridDim.y;
  int lin = blockIdx.y * gx + blockIdx.x;
  lin = (lin & 7) * (nwg >> 3) + (lin >> 3);
  const int bx = lin % gx;
  const int by = lin / gx;

  const int row0 = by * 128;
  const int col0 = bx * 128;
  const bf16* Ab = Amat + (size_t)bz * M * K;
  const bf16* Bb = Bmat + (size_t)bz * N * K;

  // union: staging (2 x 16384 B, 128x64 bf16 each) and epilogue 64x132 fp32
  __shared__ char smem[33792];
  bf16*  ldsA = (bf16*)smem;
  bf16*  ldsB = (bf16*)(smem + 16384);
  float* ldsW = (float*)smem;

  const int tid  = threadIdx.x;
  const int wave = tid >> 6;
  const int lane = tid & 63;
  const int wr   = wave >> 1;
  const int wc   = wave & 1;
  const int q    = lane >> 4;
  const int c16  = lane & 15;

  // staging source coords (swizzled)
  const int srow = lane >> 3;
  const int scol = ((lane & 7) ^ srow) * 8;

  f32x4 acc[4][4] = {};

  for (int k0 = kbeg; k0 < kend; k0 += 64) {
#pragma unroll
    for (int i = 0; i < 4; ++i) {
      int slot = wave * 4 + i;                      // 0..15, 8 rows each
      int r = slot * 8 + srow;
      __builtin_amdgcn_global_load_lds(
          (const __attribute__((address_space(1))) void*)(Ab + (size_t)(row0 + r) * K + (k0 + scol)),
          (__attribute__((address_space(3))) void*)(ldsA + slot * 512), 16, 0, 0);
      __builtin_amdgcn_global_load_lds(
          (const __attribute__((address_space(1))) void*)(Bb + (size_t)(col0 + r) * K + (k0 + scol)),
          (__attribute__((address_space(3))) void*)(ldsB + slot * 512), 16, 0, 0);
    }
    __syncthreads();

#pragma unroll
    for (int kk = 0; kk < 2; ++kk) {
      bf16x8 afr[4], bfr[4];
#pragma unroll
      for (int mt = 0; mt < 4; ++mt) {
        int R = wr * 64 + mt * 16 + c16;
        int p = ((kk << 2) + q) ^ (c16 & 7);
        afr[mt] = *(const bf16x8*)(ldsA + (size_t)R * 64 + p * 8);
      }
#pragma unroll
      for (int nt = 0; nt < 4; ++nt) {
        int R = wc * 64 + nt * 16 + c16;
        int p = ((kk << 2) + q) ^ (c16 & 7);
        bfr[nt] = *(const bf16x8*)(ldsB + (size_t)R * 64 + p * 8);
      }
#pragma unroll
      for (int mt = 0; mt < 4; ++mt)
#pragma unroll
        for (int nt = 0; nt < 4; ++nt)
          acc[mt][nt] = __builtin_amdgcn_mfma_f32_16x16x32_bf16(afr[mt], bfr[nt], acc[mt][nt], 0, 0, 0);
    }
    __syncthreads();
  }

  // C/D layout: col = lane&15, row = (lane>>4)*4 + reg (m89-verified)
  const int rowBase = row0 + wr * 64 + q * 4;
  const int colBase = col0 + wc * 64 + c16;

  if (MODE == 1) {
    // phase 1: w = rcp(sqrt(max(m2+v2-2P,0)) + eps), in place (fast approx)
    const float* m2b = m2 + (size_t)bz * M;
    const float* v2b = v2 + (size_t)bz * N;
    float v2v[4];
#pragma unroll
    for (int nt = 0; nt < 4; ++nt) v2v[nt] = v2b[colBase + nt * 16];
#pragma unroll
    for (int mt = 0; mt < 4; ++mt)
#pragma unroll
      for (int r = 0; r < 4; ++r) {
        float m2v = m2b[rowBase + mt * 16 + r];
#pragma unroll
        for (int nt = 0; nt < 4; ++nt) {
          float d2 = fmaxf(m2v + v2v[nt] - 2.f * acc[mt][nt][r], 0.f);
          acc[mt][nt][r] = __builtin_amdgcn_rcpf(__builtin_amdgcn_sqrtf(d2) + EPSILON);
        }
      }
  }

  // phase 2: LDS transpose in 2 halves of 64 rows -> vectorized global I/O
  const int lr  = tid >> 3;   // 0..31
  const int sub = tid & 7;    // 0..7  16-col chunk
#pragma unroll
  for (int h = 0; h < 2; ++h) {
    __syncthreads();  // protect LDS reuse (staging buffers / previous half)
    if (wr == h) {
#pragma unroll
      for (int mt = 0; mt < 4; ++mt)
#pragma unroll
        for (int nt = 0; nt < 4; ++nt)
#pragma unroll
          for (int r = 0; r < 4; ++r)
            ldsW[(mt * 16 + q * 4 + r) * 132 + wc * 64 + nt * 16 + c16] = acc[mt][nt][r];
    }
    __syncthreads();
#pragma unroll
    for (int h2 = 0; h2 < 2; ++h2) {
      int rloc = lr + 32 * h2;            // 0..63
      int gi = row0 + 64 * h + rloc;
      const float* wp = ldsW + rloc * 132 + sub * 16;
      float4 w0 = *(const float4*)(wp + 0);
      float4 w1 = *(const float4*)(wp + 4);
      float4 w2 = *(const float4*)(wp + 8);
      float4 w3 = *(const float4*)(wp + 12);
      float wv_[16] = { w0.x, w0.y, w0.z, w0.w, w1.x, w1.y, w1.z, w1.w,
                        w2.x, w2.y, w2.z, w2.w, w3.x, w3.y, w3.z, w3.w };
      if (MODE == 1) {
        const bf16* ap = Aw + (size_t)bz * M * N + (size_t)gi * N + (col0 + sub * 16);
        bf16x8 a0 = *(const bf16x8*)(ap);
        bf16x8 a1 = *(const bf16x8*)(ap + 8);
        bf16x8 o0, o1;
        float rs = 0.f;
#pragma unroll
        for (int e = 0; e < 8; ++e) {
          float x0 = wv_[e] * (float)a0[e];
          float x1 = wv_[e + 8] * (float)a1[e];
          o0[e] = (bf16)x0; o1[e] = (bf16)x1;
          rs += fabsf(x0) + fabsf(x1);
        }
        bf16* op = Wout + (size_t)bz * M * N + (size_t)gi * N + (col0 + sub * 16);
        *(bf16x8*)(op)     = o0;
        *(bf16x8*)(op + 8) = o1;
        rs += __shfl_xor(rs, 1);
        rs += __shfl_xor(rs, 2);
        rs += __shfl_xor(rs, 4);
        if (sub == 0) l1p[((size_t)bx * NB + bz) * M + gi] = rs;
      } else {
        bf16* Cb = Cp + ((size_t)ks * NB + bz) * ((size_t)M * N);
        bf16x8 o0, o1;
#pragma unroll
        for (int e = 0; e < 8; ++e) { o0[e] = (bf16)wv_[e]; o1[e] = (bf16)wv_[e + 8]; }
        bf16* op = Cb + (size_t)gi * N + (col0 + sub * 16);
        *(bf16x8*)(op)     = o0;
        *(bf16x8*)(op + 8) = o1;
      }
    }
  }
}

// ---------------- reduce split-K=2 bf16 partials ----------------
// RMODE 0: Mbf + m2 ;  1: scale 1/l1 -> Mbf + m2 ;  2: scale 1/l1 -> fp32 out
template <int RMODE>
__global__ void reduce_kernel(const bf16* __restrict__ part, const float* __restrict__ l1p,
                              bf16* __restrict__ Mo, float* __restrict__ Fo,
                              float* __restrict__ m2) {
  int wave = threadIdx.x >> 6, lane = threadIdx.x & 63;
  int rg = blockIdx.x * 4 + wave;          // 0..NB*S-1
  const bf16* p0 = part + (size_t)rg * D_DIM + lane * 8;
  const bf16* p1 = p0 + (size_t)NB * S_DIM * D_DIM;
  bf16x8 a = *(const bf16x8*)p0;
  bf16x8 b = *(const bf16x8*)p1;
  float v[8];
#pragma unroll
  for (int e = 0; e < 8; ++e) v[e] = (float)a[e] + (float)b[e];
  float sc = 1.f;
  if (RMODE >= 1) {
    int bb = rg >> 11, row = rg & (S_DIM - 1);
    float l1v = 0.f;
#pragma unroll
    for (int e = 0; e < 16; ++e) l1v += l1p[((size_t)e * NB + bb) * S_DIM + row];
    sc = __builtin_amdgcn_rcpf(fmaxf(l1v, 1e-12f));
  }
  float s = 0.f;
#pragma unroll
  for (int e = 0; e < 8; ++e) { v[e] *= sc; s += v[e] * v[e]; }
  if (RMODE == 2) {
    float4 o0 = { v[0], v[1], v[2], v[3] }, o1 = { v[4], v[5], v[6], v[7] };
    float* op = Fo + (size_t)rg * D_DIM + lane * 8;
    *(float4*)(op) = o0; *(float4*)(op + 4) = o1;
  } else {
    bf16x8 o;
#pragma unroll
    for (int e = 0; e < 8; ++e) o[e] = (bf16)v[e];
    *(bf16x8*)(Mo + (size_t)rg * D_DIM + lane * 8) = o;
#pragma unroll
    for (int off = 32; off > 0; off >>= 1) s += __shfl_xor(s, off);
    if (lane == 0) m2[rg] = s;
  }
}

extern "C" void kernel_launch(void* const* d_in, const int* in_sizes, int n_in,
                              void* d_out, int out_size, void* d_ws, size_t ws_size,
                              hipStream_t stream) {
  const float* A = (const float*)d_in[0];  // (4, 2048, 2048)
  const float* V = (const float*)d_in[1];  // (4, 2048, 512)
  float* out = (float*)d_out;              // (4, 2048, 512) fp32

  char* ws = (char*)d_ws;
  bf16* Abf = (bf16*)ws;   ws += (size_t)NB * S_DIM * S_DIM * 2;       // 33.5 MB
  bf16* Vbf = (bf16*)ws;   ws += (size_t)NB * S_DIM * D_DIM * 2;       //  8.4 MB
  bf16* Vt  = (bf16*)ws;   ws += (size_t)NB * S_DIM * D_DIM * 2;       //  8.4 MB
  bf16* Mbf = (bf16*)ws;   ws += (size_t)NB * S_DIM * D_DIM * 2;       //  8.4 MB
  bf16* Wbf = (bf16*)ws;   ws += (size_t)NB * S_DIM * S_DIM * 2;       // 33.5 MB
  bf16* part = (bf16*)ws;  ws += (size_t)2 * NB * S_DIM * D_DIM * 2;   // 16.8 MB
  float* v2 = (float*)ws;  ws += (size_t)NB * S_DIM * 4;
  float* m2 = (float*)ws;  ws += (size_t)NB * S_DIM * 4;
  float* l1p = (float*)ws; ws += (size_t)16 * NB * S_DIM * 4;          // 512 KB

  int nA4 = NB * S_DIM * S_DIM / 4;
  cast_kernel<<<nA4 / 256, 256, 0, stream>>>(A, Abf, nA4);
  vprep_kernel<<<dim3(S_DIM / 64, NB), 256, 0, stream>>>(V, Vbf, Vt, v2);

  // M0 = A @ V  (split-K=2 bf16 partials -> reduce with m2)
  gemm_kernel<4><<<dim3(D_DIM / 128, S_DIM / 128, NB * 2), 256, 0, stream>>>(
      Abf, Vt, S_DIM, D_DIM, S_DIM, part, nullptr, nullptr, nullptr, nullptr, nullptr);
  reduce_kernel<0><<<NB * S_DIM / 4, 256, 0, stream>>>(part, nullptr, Mbf, nullptr, m2);

  for (int it = 0; it < 3; ++it) {
    // P = M @ V^T fused with dist/weight epilogue -> Wbf, l1p
    gemm_kernel<1><<<dim3(S_DIM / 128, S_DIM / 128, NB), 256, 0, stream>>>(
        Mbf, Vbf, S_DIM, S_DIM, D_DIM, nullptr, m2, v2, Abf, Wbf, l1p);
    // M = (W @ V) / l1  (split-K=2 bf16 partials -> reduce)
    gemm_kernel<4><<<dim3(D_DIM / 128, S_DIM / 128, NB * 2), 256, 0, stream>>>(
        Wbf, Vt, S_DIM, D_DIM, S_DIM, part, nullptr, nullptr, nullptr, nullptr, nullptr);
    if (it < 2)
      reduce_kernel<1><<<NB * S_DIM / 4, 256, 0, stream>>>(part, l1p, Mbf, nullptr, m2);
    else
      reduce_kernel<2><<<NB * S_DIM / 4, 256, 0, stream>>>(part, l1p, nullptr, out, nullptr);
  }
}